// Round 18
// baseline (307.015 us; speedup 1.0000x reference)
//
#include <hip/hip_runtime.h>
#include <stdint.h>

#define Sq   2176
#define Dm   3072
#define NDm  9216
#define NH   24
#define HDm  128
#define BLKR 1152   // S - COND
#define KVH  1088   // KV half-range per split
#define NT2  34     // 32-key tiles per split
#define N8HS 835584     // Sq*Dm/8
#define N8W  1179648    // Dm*Dm/8
#define NB_CVT   3264   // N8HS/256
#define NB_W     13824  // 3*N8W/256
#define NB_LORAT 256    // 1024 rows / 4

typedef __attribute__((ext_vector_type(8))) __bf16 bf16x8;
typedef __attribute__((ext_vector_type(4))) float f32x4;
typedef __attribute__((ext_vector_type(8))) unsigned short ushort8;

#define AS1 __attribute__((address_space(1)))
#define AS3 __attribute__((address_space(3)))

__device__ __forceinline__ unsigned short f2bf(float x) {
  unsigned u = __builtin_bit_cast(unsigned, x);
  u += 0x7FFFu + ((u >> 16) & 1u);   // RNE; inputs are finite randoms
  return (unsigned short)(u >> 16);
}
__device__ __forceinline__ float bf2f(unsigned short x) {
  return __builtin_bit_cast(float, (unsigned)x << 16);
}

// ------- fused prep: cvt(hs) + cvt3(Wq,Wk,Wv) + lorat, role by blockIdx ----
__global__ __launch_bounds__(256) void prep_kernel(
    const float* __restrict__ hs,
    const float* __restrict__ w0, const float* __restrict__ w1,
    const float* __restrict__ w2,
    const float* __restrict__ k_down, const float* __restrict__ v_down,
    unsigned short* __restrict__ hsb, unsigned short* __restrict__ wb,
    float* __restrict__ tkW, float* __restrict__ tvW) {
  __shared__ float hsl[4 * Dm];      // 48 KB (lorat role)
  __shared__ float tl[4][32];
  int bid = blockIdx.x, t = threadIdx.x;

  if (bid < NB_CVT) {                // ---- cvt hs -> bf16 ----
    int i = bid * 256 + t;
    const float4* s4 = (const float4*)hs + (size_t)i * 2;
    float4 a = s4[0], b = s4[1];
    ushort8 o;
    o[0]=f2bf(a.x); o[1]=f2bf(a.y); o[2]=f2bf(a.z); o[3]=f2bf(a.w);
    o[4]=f2bf(b.x); o[5]=f2bf(b.y); o[6]=f2bf(b.z); o[7]=f2bf(b.w);
    *((ushort8*)hsb + i) = o;
    return;
  }
  if (bid < NB_CVT + NB_W) {         // ---- cvt weights -> bf16 ----
    int idx = (bid - NB_CVT) * 256 + t;
    int mat = idx < N8W ? 0 : (idx < 2 * N8W ? 1 : 2);
    int i = idx - mat * N8W;
    const float* src = mat == 0 ? w0 : (mat == 1 ? w1 : w2);
    const float4* s4 = (const float4*)src + (size_t)i * 2;
    float4 a = s4[0], b = s4[1];
    ushort8 o;
    o[0]=f2bf(a.x); o[1]=f2bf(a.y); o[2]=f2bf(a.z); o[3]=f2bf(a.w);
    o[4]=f2bf(b.x); o[5]=f2bf(b.y); o[6]=f2bf(b.z); o[7]=f2bf(b.w);
    *((ushort8*)wb + (size_t)mat * (Dm * (size_t)Dm / 8) + i) = o;
    return;
  }
  // ---- lorat: 4 rows/block ----
  int bid2 = bid - (NB_CVT + NB_W);
  int r0 = bid2 * 4;
  for (int e = t; e < 4 * Dm; e += 256)
    hsl[e] = hs[((size_t)BLKR + r0) * Dm + e];
  __syncthreads();
  int dot = t >> 3, part = t & 7;
  int mat = dot >> 4, j = dot & 15;
  const float* down = mat ? v_down : k_down;
  float p0 = 0.f, p1 = 0.f, p2 = 0.f, p3 = 0.f;
  for (int e = part; e < Dm; e += 8) {
    float dv = down[j * Dm + e];
    p0 = fmaf(hsl[e], dv, p0);
    p1 = fmaf(hsl[Dm + e], dv, p1);
    p2 = fmaf(hsl[2 * Dm + e], dv, p2);
    p3 = fmaf(hsl[3 * Dm + e], dv, p3);
  }
#pragma unroll
  for (int d = 1; d < 8; d <<= 1) {
    p0 += __shfl_xor(p0, d, 64);
    p1 += __shfl_xor(p1, d, 64);
    p2 += __shfl_xor(p2, d, 64);
    p3 += __shfl_xor(p3, d, 64);
  }
  if (part == 0) { tl[0][dot] = p0; tl[1][dot] = p1; tl[2][dot] = p2; tl[3][dot] = p3; }
  __syncthreads();
  if (t < 128) {
    int rr = t >> 5, jj = t & 31;
    float v = tl[rr][jj];
    if (jj < 16) tkW[(size_t)(r0 + rr) * 16 + jj] = v;
    else         tvW[(size_t)(r0 + rr) * 16 + (jj - 16)] = v;
  }
}

// ------- fused QKV GEMM + bias + LoRA + RMSNorm + RoPE + V-transpose ------
// (round-13 proven kernel, unchanged)
__global__ __launch_bounds__(256, 4) void gemm_kernel(
    const unsigned short* __restrict__ A,
    const unsigned short* __restrict__ B,
    const float* __restrict__ bq, const float* __restrict__ bk,
    const float* __restrict__ bv,
    const float* __restrict__ tkW, const float* __restrict__ tvW,
    const float* __restrict__ kup, const float* __restrict__ vup,
    const float* __restrict__ nqw, const float* __restrict__ nkw,
    const float* __restrict__ rc, const float* __restrict__ rs,
    unsigned short* __restrict__ qh, unsigned short* __restrict__ kh,
    unsigned short* __restrict__ vtb) {
  __shared__ __attribute__((aligned(16))) unsigned short sm[17408]; // 34.8KB
  __shared__ float rsum[2][2][64];
  int t = threadIdx.x;
  int wid = t >> 6, lane = t & 63;
  int lr = lane & 15, lg = lane >> 4;
  int wr = wid >> 1, wc = wid & 1;

  int bid = blockIdx.x;
  int wg = (bid & 7) * 129 + (bid >> 3);
  int mt, nt;
  if (wg < 216) { nt = wg / 9; mt = wg % 9; }
  else { int r2 = wg - 216; nt = 24 + r2 / 17; mt = r2 % 17; }
  int m0 = mt * 128, n0 = nt * 128;

  f32x4 acc[4][4];
#pragma unroll
  for (int m = 0; m < 4; m++)
#pragma unroll
    for (int n = 0; n < 4; n++) acc[m][n] = (f32x4){0.f, 0.f, 0.f, 0.f};

  int tr = t >> 3;
  int uu = (t & 7) ^ (tr & 7);
  const unsigned short* pA = A + (size_t)(m0 + tr) * Dm + uu * 8;
  const unsigned short* pB = B + (size_t)(n0 + tr) * Dm + uu * 8;

  int lr7 = lr & 7;
  int baseA = (wr * 64 + lr) * 64;
  int baseB = (wc * 64 + lr) * 64;
  int d0 = (lg ^ lr7) * 8;
  int d1 = ((4 + lg) ^ lr7) * 8;

  for (int kt = 0; kt < Dm / 64; kt++) {
    const int ko = kt * 64;
#pragma unroll
    for (int c = 0; c < 4; c++) {
      __builtin_amdgcn_global_load_lds(
          (const AS1 void*)(pA + (size_t)c * 32 * Dm + ko),
          (AS3 void*)(&sm[c * 2048 + wid * 512]), 16, 0, 0);
      __builtin_amdgcn_global_load_lds(
          (const AS1 void*)(pB + (size_t)c * 32 * Dm + ko),
          (AS3 void*)(&sm[8192 + c * 2048 + wid * 512]), 16, 0, 0);
    }
    __syncthreads();

    bf16x8 a0[4], b0[4];
#pragma unroll
    for (int m = 0; m < 4; m++) a0[m] = *(const bf16x8*)&sm[baseA + m * 1024 + d0];
#pragma unroll
    for (int n = 0; n < 4; n++) b0[n] = *(const bf16x8*)&sm[8192 + baseB + n * 1024 + d0];
#pragma unroll
    for (int m = 0; m < 4; m++)
#pragma unroll
      for (int n = 0; n < 4; n++)
        acc[m][n] = __builtin_amdgcn_mfma_f32_16x16x32_bf16(a0[m], b0[n], acc[m][n], 0, 0, 0);

    bf16x8 a1[4], b1[4];
#pragma unroll
    for (int m = 0; m < 4; m++) a1[m] = *(const bf16x8*)&sm[baseA + m * 1024 + d1];
#pragma unroll
    for (int n = 0; n < 4; n++) b1[n] = *(const bf16x8*)&sm[8192 + baseB + n * 1024 + d1];
#pragma unroll
    for (int m = 0; m < 4; m++)
#pragma unroll
      for (int n = 0; n < 4; n++)
        acc[m][n] = __builtin_amdgcn_mfma_f32_16x16x32_bf16(a1[m], b1[n], acc[m][n], 0, 0, 0);
    __syncthreads();
  }

  // ---- fused epilogue ----
  int region = nt < 24 ? 0 : (nt < 48 ? 1 : 2);
  int h = region == 0 ? nt : (region == 1 ? nt - 24 : nt - 48);
  int dcol[4];
#pragma unroll
  for (int n = 0; n < 4; n++) dcol[n] = wc * 64 + n * 16 + lr;
  const float* bias = region == 0 ? bq : (region == 1 ? bk : bv);
#pragma unroll
  for (int n = 0; n < 4; n++) {
    float b = bias[h * 128 + dcol[n]];
#pragma unroll
    for (int m = 0; m < 4; m++)
#pragma unroll
      for (int i = 0; i < 4; i++) acc[m][n][i] += b;
  }

  if (region >= 1 && m0 >= BLKR) {
    const float* tW = region == 1 ? tkW : tvW;
    const float* up = region == 1 ? kup : vup;
    int rr = t >> 1, half = t & 1;
    const float* srcT = tW + ((size_t)(m0 - BLKR) + rr) * 16 + half * 8;
    const float* srcU = up + ((size_t)h * 128 + rr) * 16 + half * 8;
    ushort8 vT, vU;
#pragma unroll
    for (int u2 = 0; u2 < 8; u2++) { vT[u2] = f2bf(srcT[u2]); vU[u2] = f2bf(srcU[u2]); }
    ushort8 z = {0, 0, 0, 0, 0, 0, 0, 0};
    *(ushort8*)&sm[(rr * 8 + (half ^ (rr & 7))) * 8] = vT;
    *(ushort8*)&sm[(rr * 8 + ((2 + half) ^ (rr & 7))) * 8] = z;
    *(ushort8*)&sm[8192 + (rr * 8 + (half ^ (rr & 7))) * 8] = vU;
    *(ushort8*)&sm[8192 + (rr * 8 + ((2 + half) ^ (rr & 7))) * 8] = z;
    __syncthreads();
    bf16x8 a0[4], b0[4];
#pragma unroll
    for (int m = 0; m < 4; m++) a0[m] = *(const bf16x8*)&sm[baseA + m * 1024 + d0];
#pragma unroll
    for (int n = 0; n < 4; n++) b0[n] = *(const bf16x8*)&sm[8192 + baseB + n * 1024 + d0];
#pragma unroll
    for (int m = 0; m < 4; m++)
#pragma unroll
      for (int n = 0; n < 4; n++)
        acc[m][n] = __builtin_amdgcn_mfma_f32_16x16x32_bf16(a0[m], b0[n], acc[m][n], 0, 0, 0);
    __syncthreads();
  }

  if (region <= 1) {
    float part[4][4];
#pragma unroll
    for (int m = 0; m < 4; m++)
#pragma unroll
      for (int i = 0; i < 4; i++) {
        float p = acc[m][0][i] * acc[m][0][i] + acc[m][1][i] * acc[m][1][i]
                + acc[m][2][i] * acc[m][2][i] + acc[m][3][i] * acc[m][3][i];
#pragma unroll
        for (int d = 1; d < 16; d <<= 1) p += __shfl_xor(p, d, 64);
        part[m][i] = p;
      }
    if (lr == 0) {
#pragma unroll
      for (int m = 0; m < 4; m++)
#pragma unroll
        for (int i = 0; i < 4; i++) rsum[wr][wc][m * 16 + lg * 4 + i] = part[m][i];
    }
    __syncthreads();
    const float* nw = region == 0 ? nqw : nkw;
    float wv[4];
#pragma unroll
    for (int n = 0; n < 4; n++) wv[n] = nw[dcol[n]];
    unsigned short* dstb = region == 0 ? qh : kh;
    int srows = region == 0 ? BLKR : Sq;
#pragma unroll
    for (int m = 0; m < 4; m++)
#pragma unroll
      for (int i = 0; i < 4; i++) {
        int idx = m * 16 + lg * 4 + i;
        float s2 = rsum[wr][0][idx] + rsum[wr][1][idx];
        float rinv = rsqrtf(s2 * (1.f / 128.f) + 1e-6f);
        int r = m0 + wr * 64 + idx;
#pragma unroll
        for (int n = 0; n < 4; n++) {
          float xn = acc[m][n][i] * rinv * wv[n];
          float xp = __shfl_xor(xn, 1, 64);
          float c = rc[r * 128 + dcol[n]];
          float s = rs[r * 128 + dcol[n]];
          float rot = (dcol[n] & 1) ? xp : -xp;
          dstb[((size_t)h * srows + r) * 128 + dcol[n]] = f2bf(xn * c + rot * s);
        }
      }
  } else {
#pragma unroll
    for (int m = 0; m < 4; m++)
#pragma unroll
      for (int i = 0; i < 4; i++) {
        int rl = wr * 64 + m * 16 + lg * 4 + i;
#pragma unroll
        for (int n = 0; n < 4; n++)
          sm[dcol[n] * 136 + rl] = f2bf(acc[m][n][i]);
      }
    __syncthreads();
    int d = t >> 1, rc0 = (t & 1) * 64;
    unsigned short* dv = vtb + ((size_t)h * 128 + d) * Sq + m0 + rc0;
#pragma unroll
    for (int u = 0; u < 8; u++)
      *(ushort8*)(dv + u * 8) = *(const ushort8*)&sm[d * 136 + rc0 + u * 8];
  }
}

// ------- flash attention v7: T3/T4 minimal — 3-buffer rotation, ONE raw
// barrier per tile, counted vmcnt(4) (never drains to 0 in the loop).
// Safety: vmcnt(4) before the barrier => after barrier, all waves' stage(kt)
// writes landed. Overwrite: stage(kt+1) hits the buffer last read by
// compute(kt-2); reaching this point requires passing BARRIER(kt-1), which
// all waves reach only after compute(kt-2) (ds_reads drained by data-dep).
__global__ __launch_bounds__(256) void attn_kernel(
    const unsigned short* __restrict__ qh,  // [NH][1152][128]
    const unsigned short* __restrict__ kh,  // [NH][2176][128]
    const unsigned short* __restrict__ vt,  // [NH][128][2176]
    unsigned short* __restrict__ accW,      // [2][1152][3072] bf16 partials
    float* __restrict__ lW) {               // [2][24][1152] partial lsum
  int bid = blockIdx.x;
  int wg = (bid & 7) * 108 + (bid >> 3);    // bijective: 864 = 8 x 108
  int h = wg / 36, rem = wg % 36;
  int qt = rem >> 1, split = rem & 1;
  int q0 = qt * 64;
  int k0 = split * KVH;

  int t = threadIdx.x;
  int w = t >> 6, lane = t & 63;
  int lr = lane & 15, lg = lane >> 4;

  __shared__ __attribute__((aligned(16))) unsigned short kLds[3][32 * 128];
  __shared__ __attribute__((aligned(16))) unsigned short vLds[3][128 * 32];

  const unsigned short* qb = qh + ((size_t)h * BLKR + q0 + w * 16) * 128;
  bf16x8 aq[4];
#pragma unroll
  for (int m = 0; m < 4; m++)
    aq[m] = *(const bf16x8*)(qb + (size_t)lr * 128 + m * 32 + lg * 8);

  const unsigned short* kh_h = kh + ((size_t)h * Sq + k0) * 128;
  const unsigned short* vt_h = vt + (size_t)h * 128 * Sq + k0;

  const unsigned short* srcK[2];
  const unsigned short* srcV[2];
  int kDst[2], vDst[2];
#pragma unroll
  for (int c = 0; c < 2; c++) {
    int u = c * 256 + t;
    int rK = u >> 4, sK = u & 15;
    srcK[c] = kh_h + (size_t)rK * 128 + ((sK ^ (rK & 7)) * 8);
    kDst[c] = u * 8;
    int rV = u >> 2, sV = u & 3;
    srcV[c] = vt_h + (size_t)rV * Sq + ((sV ^ (rV & 3)) * 8);
    vDst[c] = u * 8;
  }

  auto stage = [&](int kt, int buf) {
#pragma unroll
    for (int c = 0; c < 2; c++)
      __builtin_amdgcn_global_load_lds(
          (const AS1 void*)(srcK[c] + (size_t)kt * 4096),
          (AS3 void*)(&kLds[buf][kDst[c]]), 16, 0, 0);
#pragma unroll
    for (int c = 0; c < 2; c++)
      __builtin_amdgcn_global_load_lds(
          (const AS1 void*)(srcV[c] + (size_t)kt * 32),
          (AS3 void*)(&vLds[buf][vDst[c]]), 16, 0, 0);
  };

  f32x4 acc[8];
#pragma unroll
  for (int o = 0; o < 8; o++) acc[o] = (f32x4){0.f, 0.f, 0.f, 0.f};
  float lsum = 0.f;
  const float sc = 0.08838834764831845f;   // 1/sqrt(128)
  const float L2E = 1.4426950408889634f;
  const float ea = sc * L2E, eb = -10.0f * L2E;   // fixed M = 10

  int lr7 = lr & 7, lr3 = lr & 3;
  int adLo = ((((lg & 1) << 1)) * 16 + lr) * 4;
  int adHi = adLo + 64;
  bool hiKb = (lg & 2) != 0;

  auto compute = [&](int buf) {
    const unsigned short* kbuf = kLds[buf];
    const unsigned short* vbuf = vLds[buf];
    f32x4 s2[2];
    s2[0] = (f32x4){0.f, 0.f, 0.f, 0.f};
    s2[1] = (f32x4){0.f, 0.f, 0.f, 0.f};
    __builtin_amdgcn_s_setprio(1);
#pragma unroll
    for (int kb = 0; kb < 2; kb++)
#pragma unroll
      for (int m = 0; m < 4; m++) {
        bf16x8 kf = *(const bf16x8*)&kbuf[(kb * 16 + lr) * 128 + ((m * 4 + lg) ^ lr7) * 8];
        s2[kb] = __builtin_amdgcn_mfma_f32_16x16x32_bf16(kf, aq[m], s2[kb], 0, 0, 0);
      }
    __builtin_amdgcn_s_setprio(0);
    unsigned pk0[2], pk1[2];
#pragma unroll
    for (int kb = 0; kb < 2; kb++) {
      float p0 = exp2f(fmaf(s2[kb][0], ea, eb));
      float p1 = exp2f(fmaf(s2[kb][1], ea, eb));
      float p2 = exp2f(fmaf(s2[kb][2], ea, eb));
      float p3 = exp2f(fmaf(s2[kb][3], ea, eb));
      lsum += (p0 + p1) + (p2 + p3);
      unsigned r0, r1;
      asm("v_cvt_pk_bf16_f32 %0, %1, %2" : "=v"(r0) : "v"(p0), "v"(p1));
      asm("v_cvt_pk_bf16_f32 %0, %1, %2" : "=v"(r1) : "v"(p2), "v"(p3));
      if (kb == 0) { pk0[0] = r0; pk0[1] = r1; }
      else         { pk1[0] = r0; pk1[1] = r1; }
    }
    int a00 = __builtin_amdgcn_ds_bpermute(adLo, (int)pk0[0]);
    int a01 = __builtin_amdgcn_ds_bpermute(adLo, (int)pk0[1]);
    int a10 = __builtin_amdgcn_ds_bpermute(adLo, (int)pk1[0]);
    int a11 = __builtin_amdgcn_ds_bpermute(adLo, (int)pk1[1]);
    int b00 = __builtin_amdgcn_ds_bpermute(adHi, (int)pk0[0]);
    int b01 = __builtin_amdgcn_ds_bpermute(adHi, (int)pk0[1]);
    int b10 = __builtin_amdgcn_ds_bpermute(adHi, (int)pk1[0]);
    int b11 = __builtin_amdgcn_ds_bpermute(adHi, (int)pk1[1]);
    int4 pw;
    pw.x = hiKb ? a10 : a00;
    pw.y = hiKb ? a11 : a01;
    pw.z = hiKb ? b10 : b00;
    pw.w = hiKb ? b11 : b01;
    bf16x8 pfrag = __builtin_bit_cast(bf16x8, pw);
    __builtin_amdgcn_s_setprio(1);
#pragma unroll
    for (int o = 0; o < 8; o++) {
      bf16x8 vf = *(const bf16x8*)&vbuf[(o * 16 + lr) * 32 + (lg ^ lr3) * 8];
      acc[o] = __builtin_amdgcn_mfma_f32_16x16x32_bf16(vf, pfrag, acc[o], 0, 0, 0);
    }
    __builtin_amdgcn_s_setprio(0);
  };

  stage(0, 0);
  for (int kt = 0; kt < NT2; kt++) {
    if (kt + 1 < NT2) {
      stage(kt + 1, (kt + 1) % 3);
      asm volatile("s_waitcnt vmcnt(4)" ::: "memory");   // stage(kt) landed; kt+1 in flight
    } else {
      asm volatile("s_waitcnt vmcnt(0)" ::: "memory");   // final tile
    }
    __builtin_amdgcn_sched_barrier(0);
    __builtin_amdgcn_s_barrier();                         // raw: no drain
    compute(kt % 3);
  }

  lsum += __shfl_xor(lsum, 16, 64);
  lsum += __shfl_xor(lsum, 32, 64);

  unsigned short* accP = accW + (size_t)split * BLKR * 3072;
  size_t rowOff = (size_t)(q0 + w * 16 + lr) * 3072 + h * 128;
#pragma unroll
  for (int o = 0; o < 8; o++) {
    ushort4 o4 = make_ushort4(f2bf(acc[o][0]), f2bf(acc[o][1]),
                              f2bf(acc[o][2]), f2bf(acc[o][3]));
    *(ushort4*)&accP[rowOff + o * 16 + lg * 4] = o4;
  }
  if (lg == 0) {
    float* lP = lW + (size_t)split * NH * BLKR + (size_t)h * BLKR;
    lP[q0 + w * 16 + lr] = lsum;
  }
}

// ---------------- combine: out = (a0+a1)/(l0+l1), bf16 partials ----------
__global__ __launch_bounds__(256) void normalize_kernel(
    const unsigned short* __restrict__ accW, const float* __restrict__ lW,
    float* __restrict__ out) {
  int idx = blockIdx.x * 256 + threadIdx.x;      // 442368 total
  int r = idx / 384, rem = idx % 384;
  int c = rem * 8, h = c >> 7;
  ushort8 u0 = *(const ushort8*)(accW + (size_t)r * 3072 + c);
  ushort8 u1 = *(const ushort8*)(accW + (size_t)BLKR * 3072 + (size_t)r * 3072 + c);
  float l = lW[(size_t)h * BLKR + r] + lW[(size_t)NH * BLKR + (size_t)h * BLKR + r];
  float inv = 1.0f / l;
  float4 o0, o1;
  o0.x = (bf2f(u0[0]) + bf2f(u1[0])) * inv;
  o0.y = (bf2f(u0[1]) + bf2f(u1[1])) * inv;
  o0.z = (bf2f(u0[2]) + bf2f(u1[2])) * inv;
  o0.w = (bf2f(u0[3]) + bf2f(u1[3])) * inv;
  o1.x = (bf2f(u0[4]) + bf2f(u1[4])) * inv;
  o1.y = (bf2f(u0[5]) + bf2f(u1[5])) * inv;
  o1.z = (bf2f(u0[6]) + bf2f(u1[6])) * inv;
  o1.w = (bf2f(u0[7]) + bf2f(u1[7])) * inv;
  float4* op = (float4*)(out + (size_t)r * 3072 + c);
  op[0] = o0; op[1] = o1;
}

extern "C" void kernel_launch(void* const* d_in, const int* in_sizes, int n_in,
                              void* d_out, int out_size, void* d_ws, size_t ws_size,
                              hipStream_t stream) {
  const float* hs  = (const float*)d_in[0];
  const float* Wq  = (const float*)d_in[1];
  const float* bq  = (const float*)d_in[2];
  const float* Wk  = (const float*)d_in[3];
  const float* bk  = (const float*)d_in[4];
  const float* Wv  = (const float*)d_in[5];
  const float* bv  = (const float*)d_in[6];
  const float* k_down = (const float*)d_in[9];
  const float* k_up   = (const float*)d_in[10];
  const float* v_down = (const float*)d_in[11];
  const float* v_up   = (const float*)d_in[12];
  const float* nqw = (const float*)d_in[13];
  const float* nkw = (const float*)d_in[14];
  const float* rc  = (const float*)d_in[15];
  const float* rsn = (const float*)d_in[16];
  float* out = (float*)d_out;

  char* ws = (char*)d_ws;
  unsigned short* hsb = (unsigned short*)(ws + 0);          // 13,369,344 B
  unsigned short* wb  = (unsigned short*)(ws + 13369344);   // 56,623,104 B
  unsigned short* accW = (unsigned short*)(ws + 69992448);  // 14,155,776 B (bf16)
  float* lW   = (float*)(ws + 98304000);                    //    221,184 B
  float* tkW  = (float*)(ws + 98525184);                    //     65,536 B
  float* tvW  = (float*)(ws + 98590720);                    //     65,536 B
  unsigned short* qh  = (unsigned short*)(ws + 150208512);  //  7,077,888 B
  unsigned short* kh  = (unsigned short*)(ws + 157286400);  // 13,369,344 B
  unsigned short* vtb = (unsigned short*)(ws + 170655744);  // 13,369,344 B

  prep_kernel<<<dim3(NB_CVT + NB_W + NB_LORAT), 256, 0, stream>>>(
      hs, Wq, Wk, Wv, k_down, v_down, hsb, wb, tkW, tvW);

  gemm_kernel<<<dim3(1032), 256, 0, stream>>>(hsb, wb, bq, bk, bv,
                                              tkW, tvW, k_up, v_up,
                                              nqw, nkw, rc, rsn, qh, kh, vtb);
  attn_kernel<<<dim3(2 * 18 * NH), 256, 0, stream>>>(qh, kh, vtb, accW, lW);
  normalize_kernel<<<dim3(BLKR * 3072 / 8 / 256), 256, 0, stream>>>(accW, lW, out);
}

// Round 19
// 297.149 us; speedup vs baseline: 1.0332x; 1.0332x over previous
//
#include <hip/hip_runtime.h>
#include <stdint.h>

#define Sq   2176
#define Dm   3072
#define NDm  9216
#define NH   24
#define HDm  128
#define BLKR 1152   // S - COND
#define NTF  68     // 32-key tiles, full KV
#define N8HS 835584     // Sq*Dm/8
#define N8W  1179648    // Dm*Dm/8
#define NB_CVT   3264   // N8HS/256
#define NB_W     13824  // 3*N8W/256
#define NB_LORAT 256    // 1024 rows / 4

typedef __attribute__((ext_vector_type(8))) __bf16 bf16x8;
typedef __attribute__((ext_vector_type(4))) float f32x4;
typedef __attribute__((ext_vector_type(8))) unsigned short ushort8;

#define AS1 __attribute__((address_space(1)))
#define AS3 __attribute__((address_space(3)))

__device__ __forceinline__ unsigned short f2bf(float x) {
  unsigned u = __builtin_bit_cast(unsigned, x);
  u += 0x7FFFu + ((u >> 16) & 1u);   // RNE; inputs are finite randoms
  return (unsigned short)(u >> 16);
}

// ------- fused prep: cvt(hs) + cvt3(Wq,Wk,Wv) + lorat, role by blockIdx ----
__global__ __launch_bounds__(256) void prep_kernel(
    const float* __restrict__ hs,
    const float* __restrict__ w0, const float* __restrict__ w1,
    const float* __restrict__ w2,
    const float* __restrict__ k_down, const float* __restrict__ v_down,
    unsigned short* __restrict__ hsb, unsigned short* __restrict__ wb,
    float* __restrict__ tkW, float* __restrict__ tvW) {
  __shared__ float hsl[4 * Dm];      // 48 KB (lorat role)
  __shared__ float tl[4][32];
  int bid = blockIdx.x, t = threadIdx.x;

  if (bid < NB_CVT) {                // ---- cvt hs -> bf16 ----
    int i = bid * 256 + t;
    const float4* s4 = (const float4*)hs + (size_t)i * 2;
    float4 a = s4[0], b = s4[1];
    ushort8 o;
    o[0]=f2bf(a.x); o[1]=f2bf(a.y); o[2]=f2bf(a.z); o[3]=f2bf(a.w);
    o[4]=f2bf(b.x); o[5]=f2bf(b.y); o[6]=f2bf(b.z); o[7]=f2bf(b.w);
    *((ushort8*)hsb + i) = o;
    return;
  }
  if (bid < NB_CVT + NB_W) {         // ---- cvt weights -> bf16 ----
    int idx = (bid - NB_CVT) * 256 + t;
    int mat = idx < N8W ? 0 : (idx < 2 * N8W ? 1 : 2);
    int i = idx - mat * N8W;
    const float* src = mat == 0 ? w0 : (mat == 1 ? w1 : w2);
    const float4* s4 = (const float4*)src + (size_t)i * 2;
    float4 a = s4[0], b = s4[1];
    ushort8 o;
    o[0]=f2bf(a.x); o[1]=f2bf(a.y); o[2]=f2bf(a.z); o[3]=f2bf(a.w);
    o[4]=f2bf(b.x); o[5]=f2bf(b.y); o[6]=f2bf(b.z); o[7]=f2bf(b.w);
    *((ushort8*)wb + (size_t)mat * (Dm * (size_t)Dm / 8) + i) = o;
    return;
  }
  // ---- lorat: 4 rows/block ----
  int bid2 = bid - (NB_CVT + NB_W);
  int r0 = bid2 * 4;
  for (int e = t; e < 4 * Dm; e += 256)
    hsl[e] = hs[((size_t)BLKR + r0) * Dm + e];
  __syncthreads();
  int dot = t >> 3, part = t & 7;
  int mat = dot >> 4, j = dot & 15;
  const float* down = mat ? v_down : k_down;
  float p0 = 0.f, p1 = 0.f, p2 = 0.f, p3 = 0.f;
  for (int e = part; e < Dm; e += 8) {
    float dv = down[j * Dm + e];
    p0 = fmaf(hsl[e], dv, p0);
    p1 = fmaf(hsl[Dm + e], dv, p1);
    p2 = fmaf(hsl[2 * Dm + e], dv, p2);
    p3 = fmaf(hsl[3 * Dm + e], dv, p3);
  }
#pragma unroll
  for (int d = 1; d < 8; d <<= 1) {
    p0 += __shfl_xor(p0, d, 64);
    p1 += __shfl_xor(p1, d, 64);
    p2 += __shfl_xor(p2, d, 64);
    p3 += __shfl_xor(p3, d, 64);
  }
  if (part == 0) { tl[0][dot] = p0; tl[1][dot] = p1; tl[2][dot] = p2; tl[3][dot] = p3; }
  __syncthreads();
  if (t < 128) {
    int rr = t >> 5, jj = t & 31;
    float v = tl[rr][jj];
    if (jj < 16) tkW[(size_t)(r0 + rr) * 16 + jj] = v;
    else         tvW[(size_t)(r0 + rr) * 16 + (jj - 16)] = v;
  }
}

// ------- fused QKV GEMM + bias + LoRA + RMSNorm + RoPE + V-transpose ------
// (round-13/16 proven kernel, unchanged)
__global__ __launch_bounds__(256, 4) void gemm_kernel(
    const unsigned short* __restrict__ A,
    const unsigned short* __restrict__ B,
    const float* __restrict__ bq, const float* __restrict__ bk,
    const float* __restrict__ bv,
    const float* __restrict__ tkW, const float* __restrict__ tvW,
    const float* __restrict__ kup, const float* __restrict__ vup,
    const float* __restrict__ nqw, const float* __restrict__ nkw,
    const float* __restrict__ rc, const float* __restrict__ rs,
    unsigned short* __restrict__ qh, unsigned short* __restrict__ kh,
    unsigned short* __restrict__ vtb) {
  __shared__ __attribute__((aligned(16))) unsigned short sm[17408]; // 34.8KB
  __shared__ float rsum[2][2][64];
  int t = threadIdx.x;
  int wid = t >> 6, lane = t & 63;
  int lr = lane & 15, lg = lane >> 4;
  int wr = wid >> 1, wc = wid & 1;

  int bid = blockIdx.x;
  int wg = (bid & 7) * 129 + (bid >> 3);
  int mt, nt;
  if (wg < 216) { nt = wg / 9; mt = wg % 9; }
  else { int r2 = wg - 216; nt = 24 + r2 / 17; mt = r2 % 17; }
  int m0 = mt * 128, n0 = nt * 128;

  f32x4 acc[4][4];
#pragma unroll
  for (int m = 0; m < 4; m++)
#pragma unroll
    for (int n = 0; n < 4; n++) acc[m][n] = (f32x4){0.f, 0.f, 0.f, 0.f};

  int tr = t >> 3;
  int uu = (t & 7) ^ (tr & 7);
  const unsigned short* pA = A + (size_t)(m0 + tr) * Dm + uu * 8;
  const unsigned short* pB = B + (size_t)(n0 + tr) * Dm + uu * 8;

  int lr7 = lr & 7;
  int baseA = (wr * 64 + lr) * 64;
  int baseB = (wc * 64 + lr) * 64;
  int d0 = (lg ^ lr7) * 8;
  int d1 = ((4 + lg) ^ lr7) * 8;

  for (int kt = 0; kt < Dm / 64; kt++) {
    const int ko = kt * 64;
#pragma unroll
    for (int c = 0; c < 4; c++) {
      __builtin_amdgcn_global_load_lds(
          (const AS1 void*)(pA + (size_t)c * 32 * Dm + ko),
          (AS3 void*)(&sm[c * 2048 + wid * 512]), 16, 0, 0);
      __builtin_amdgcn_global_load_lds(
          (const AS1 void*)(pB + (size_t)c * 32 * Dm + ko),
          (AS3 void*)(&sm[8192 + c * 2048 + wid * 512]), 16, 0, 0);
    }
    __syncthreads();

    bf16x8 a0[4], b0[4];
#pragma unroll
    for (int m = 0; m < 4; m++) a0[m] = *(const bf16x8*)&sm[baseA + m * 1024 + d0];
#pragma unroll
    for (int n = 0; n < 4; n++) b0[n] = *(const bf16x8*)&sm[8192 + baseB + n * 1024 + d0];
#pragma unroll
    for (int m = 0; m < 4; m++)
#pragma unroll
      for (int n = 0; n < 4; n++)
        acc[m][n] = __builtin_amdgcn_mfma_f32_16x16x32_bf16(a0[m], b0[n], acc[m][n], 0, 0, 0);

    bf16x8 a1[4], b1[4];
#pragma unroll
    for (int m = 0; m < 4; m++) a1[m] = *(const bf16x8*)&sm[baseA + m * 1024 + d1];
#pragma unroll
    for (int n = 0; n < 4; n++) b1[n] = *(const bf16x8*)&sm[8192 + baseB + n * 1024 + d1];
#pragma unroll
    for (int m = 0; m < 4; m++)
#pragma unroll
      for (int n = 0; n < 4; n++)
        acc[m][n] = __builtin_amdgcn_mfma_f32_16x16x32_bf16(a1[m], b1[n], acc[m][n], 0, 0, 0);
    __syncthreads();
  }

  // ---- fused epilogue ----
  int region = nt < 24 ? 0 : (nt < 48 ? 1 : 2);
  int h = region == 0 ? nt : (region == 1 ? nt - 24 : nt - 48);
  int dcol[4];
#pragma unroll
  for (int n = 0; n < 4; n++) dcol[n] = wc * 64 + n * 16 + lr;
  const float* bias = region == 0 ? bq : (region == 1 ? bk : bv);
#pragma unroll
  for (int n = 0; n < 4; n++) {
    float b = bias[h * 128 + dcol[n]];
#pragma unroll
    for (int m = 0; m < 4; m++)
#pragma unroll
      for (int i = 0; i < 4; i++) acc[m][n][i] += b;
  }

  if (region >= 1 && m0 >= BLKR) {
    const float* tW = region == 1 ? tkW : tvW;
    const float* up = region == 1 ? kup : vup;
    int rr = t >> 1, half = t & 1;
    const float* srcT = tW + ((size_t)(m0 - BLKR) + rr) * 16 + half * 8;
    const float* srcU = up + ((size_t)h * 128 + rr) * 16 + half * 8;
    ushort8 vT, vU;
#pragma unroll
    for (int u2 = 0; u2 < 8; u2++) { vT[u2] = f2bf(srcT[u2]); vU[u2] = f2bf(srcU[u2]); }
    ushort8 z = {0, 0, 0, 0, 0, 0, 0, 0};
    *(ushort8*)&sm[(rr * 8 + (half ^ (rr & 7))) * 8] = vT;
    *(ushort8*)&sm[(rr * 8 + ((2 + half) ^ (rr & 7))) * 8] = z;
    *(ushort8*)&sm[8192 + (rr * 8 + (half ^ (rr & 7))) * 8] = vU;
    *(ushort8*)&sm[8192 + (rr * 8 + ((2 + half) ^ (rr & 7))) * 8] = z;
    __syncthreads();
    bf16x8 a0[4], b0[4];
#pragma unroll
    for (int m = 0; m < 4; m++) a0[m] = *(const bf16x8*)&sm[baseA + m * 1024 + d0];
#pragma unroll
    for (int n = 0; n < 4; n++) b0[n] = *(const bf16x8*)&sm[8192 + baseB + n * 1024 + d0];
#pragma unroll
    for (int m = 0; m < 4; m++)
#pragma unroll
      for (int n = 0; n < 4; n++)
        acc[m][n] = __builtin_amdgcn_mfma_f32_16x16x32_bf16(a0[m], b0[n], acc[m][n], 0, 0, 0);
    __syncthreads();
  }

  if (region <= 1) {
    float part[4][4];
#pragma unroll
    for (int m = 0; m < 4; m++)
#pragma unroll
      for (int i = 0; i < 4; i++) {
        float p = acc[m][0][i] * acc[m][0][i] + acc[m][1][i] * acc[m][1][i]
                + acc[m][2][i] * acc[m][2][i] + acc[m][3][i] * acc[m][3][i];
#pragma unroll
        for (int d = 1; d < 16; d <<= 1) p += __shfl_xor(p, d, 64);
        part[m][i] = p;
      }
    if (lr == 0) {
#pragma unroll
      for (int m = 0; m < 4; m++)
#pragma unroll
        for (int i = 0; i < 4; i++) rsum[wr][wc][m * 16 + lg * 4 + i] = part[m][i];
    }
    __syncthreads();
    const float* nw = region == 0 ? nqw : nkw;
    float wv[4];
#pragma unroll
    for (int n = 0; n < 4; n++) wv[n] = nw[dcol[n]];
    unsigned short* dstb = region == 0 ? qh : kh;
    int srows = region == 0 ? BLKR : Sq;
#pragma unroll
    for (int m = 0; m < 4; m++)
#pragma unroll
      for (int i = 0; i < 4; i++) {
        int idx = m * 16 + lg * 4 + i;
        float s2 = rsum[wr][0][idx] + rsum[wr][1][idx];
        float rinv = rsqrtf(s2 * (1.f / 128.f) + 1e-6f);
        int r = m0 + wr * 64 + idx;
#pragma unroll
        for (int n = 0; n < 4; n++) {
          float xn = acc[m][n][i] * rinv * wv[n];
          float xp = __shfl_xor(xn, 1, 64);
          float c = rc[r * 128 + dcol[n]];
          float s = rs[r * 128 + dcol[n]];
          float rot = (dcol[n] & 1) ? xp : -xp;
          dstb[((size_t)h * srows + r) * 128 + dcol[n]] = f2bf(xn * c + rot * s);
        }
      }
  } else {
#pragma unroll
    for (int m = 0; m < 4; m++)
#pragma unroll
      for (int i = 0; i < 4; i++) {
        int rl = wr * 64 + m * 16 + lg * 4 + i;
#pragma unroll
        for (int n = 0; n < 4; n++)
          sm[dcol[n] * 136 + rl] = f2bf(acc[m][n][i]);
      }
    __syncthreads();
    int d = t >> 1, rc0 = (t & 1) * 64;
    unsigned short* dv = vtb + ((size_t)h * 128 + d) * Sq + m0 + rc0;
#pragma unroll
    for (int u = 0; u < 8; u++)
      *(ushort8*)(dv + u * 8) = *(const ushort8*)&sm[d * 136 + rc0 + u * 8];
  }
}

// ------- flash attention v8: r16-proven pipeline, full KV, direct write ----
// No split-KV: 432 blocks, each wave owns 16 q-rows over all 68 tiles and
// writes out = acc/lsum directly (combine kernel + partial buffers deleted).
// Fixed-M softmax makes this exact. r9/r10 showed attn is occupancy-
// insensitive, so halving blocks is free.
__global__ __launch_bounds__(256) void attn_kernel(
    const unsigned short* __restrict__ qh,  // [NH][1152][128]
    const unsigned short* __restrict__ kh,  // [NH][2176][128]
    const unsigned short* __restrict__ vt,  // [NH][128][2176]
    float* __restrict__ out) {              // [1152][3072] f32
  int bid = blockIdx.x;
  int wg = (bid & 7) * 54 + (bid >> 3);     // bijective: 432 = 8 x 54
  int h = wg / 18, qt = wg % 18;
  int q0 = qt * 64;

  int t = threadIdx.x;
  int w = t >> 6, lane = t & 63;
  int lr = lane & 15, lg = lane >> 4;

  __shared__ __attribute__((aligned(16))) unsigned short kLds[2][32 * 128];
  __shared__ __attribute__((aligned(16))) unsigned short vLds[2][128 * 32];

  const unsigned short* qb = qh + ((size_t)h * BLKR + q0 + w * 16) * 128;
  bf16x8 aq[4];
#pragma unroll
  for (int m = 0; m < 4; m++)
    aq[m] = *(const bf16x8*)(qb + (size_t)lr * 128 + m * 32 + lg * 8);

  const unsigned short* kh_h = kh + (size_t)h * Sq * 128;
  const unsigned short* vt_h = vt + (size_t)h * 128 * Sq;

  const unsigned short* srcK[2];
  const unsigned short* srcV[2];
  int kDst[2], vDst[2];
#pragma unroll
  for (int c = 0; c < 2; c++) {
    int u = c * 256 + t;
    int rK = u >> 4, sK = u & 15;
    srcK[c] = kh_h + (size_t)rK * 128 + ((sK ^ (rK & 7)) * 8);
    kDst[c] = u * 8;
    int rV = u >> 2, sV = u & 3;
    srcV[c] = vt_h + (size_t)rV * Sq + ((sV ^ (rV & 3)) * 8);
    vDst[c] = u * 8;
  }

  auto stage = [&](int kt, int buf) {
#pragma unroll
    for (int c = 0; c < 2; c++)
      __builtin_amdgcn_global_load_lds(
          (const AS1 void*)(srcK[c] + (size_t)kt * 4096),
          (AS3 void*)(&kLds[buf][kDst[c]]), 16, 0, 0);
#pragma unroll
    for (int c = 0; c < 2; c++)
      __builtin_amdgcn_global_load_lds(
          (const AS1 void*)(srcV[c] + (size_t)kt * 32),
          (AS3 void*)(&vLds[buf][vDst[c]]), 16, 0, 0);
  };

  f32x4 acc[8];
#pragma unroll
  for (int o = 0; o < 8; o++) acc[o] = (f32x4){0.f, 0.f, 0.f, 0.f};
  float lsum = 0.f;
  const float sc = 0.08838834764831845f;   // 1/sqrt(128)
  const float L2E = 1.4426950408889634f;
  const float ea = sc * L2E, eb = -10.0f * L2E;   // fixed M = 10

  int lr7 = lr & 7, lr3 = lr & 3;
  int adLo = ((((lg & 1) << 1)) * 16 + lr) * 4;
  int adHi = adLo + 64;
  bool hiKb = (lg & 2) != 0;

  auto compute = [&](int buf) {
    const unsigned short* kbuf = kLds[buf];
    const unsigned short* vbuf = vLds[buf];
    f32x4 s2[2];
    s2[0] = (f32x4){0.f, 0.f, 0.f, 0.f};
    s2[1] = (f32x4){0.f, 0.f, 0.f, 0.f};
    __builtin_amdgcn_s_setprio(1);
#pragma unroll
    for (int kb = 0; kb < 2; kb++)
#pragma unroll
      for (int m = 0; m < 4; m++) {
        bf16x8 kf = *(const bf16x8*)&kbuf[(kb * 16 + lr) * 128 + ((m * 4 + lg) ^ lr7) * 8];
        s2[kb] = __builtin_amdgcn_mfma_f32_16x16x32_bf16(kf, aq[m], s2[kb], 0, 0, 0);
      }
    __builtin_amdgcn_s_setprio(0);
    unsigned pk0[2], pk1[2];
#pragma unroll
    for (int kb = 0; kb < 2; kb++) {
      float p0 = exp2f(fmaf(s2[kb][0], ea, eb));
      float p1 = exp2f(fmaf(s2[kb][1], ea, eb));
      float p2 = exp2f(fmaf(s2[kb][2], ea, eb));
      float p3 = exp2f(fmaf(s2[kb][3], ea, eb));
      lsum += (p0 + p1) + (p2 + p3);
      unsigned r0, r1;
      asm("v_cvt_pk_bf16_f32 %0, %1, %2" : "=v"(r0) : "v"(p0), "v"(p1));
      asm("v_cvt_pk_bf16_f32 %0, %1, %2" : "=v"(r1) : "v"(p2), "v"(p3));
      if (kb == 0) { pk0[0] = r0; pk0[1] = r1; }
      else         { pk1[0] = r0; pk1[1] = r1; }
    }
    int a00 = __builtin_amdgcn_ds_bpermute(adLo, (int)pk0[0]);
    int a01 = __builtin_amdgcn_ds_bpermute(adLo, (int)pk0[1]);
    int a10 = __builtin_amdgcn_ds_bpermute(adLo, (int)pk1[0]);
    int a11 = __builtin_amdgcn_ds_bpermute(adLo, (int)pk1[1]);
    int b00 = __builtin_amdgcn_ds_bpermute(adHi, (int)pk0[0]);
    int b01 = __builtin_amdgcn_ds_bpermute(adHi, (int)pk0[1]);
    int b10 = __builtin_amdgcn_ds_bpermute(adHi, (int)pk1[0]);
    int b11 = __builtin_amdgcn_ds_bpermute(adHi, (int)pk1[1]);
    int4 pw;
    pw.x = hiKb ? a10 : a00;
    pw.y = hiKb ? a11 : a01;
    pw.z = hiKb ? b10 : b00;
    pw.w = hiKb ? b11 : b01;
    bf16x8 pfrag = __builtin_bit_cast(bf16x8, pw);
    __builtin_amdgcn_s_setprio(1);
#pragma unroll
    for (int o = 0; o < 8; o++) {
      bf16x8 vf = *(const bf16x8*)&vbuf[(o * 16 + lr) * 32 + (lg ^ lr3) * 8];
      acc[o] = __builtin_amdgcn_mfma_f32_16x16x32_bf16(vf, pfrag, acc[o], 0, 0, 0);
    }
    __builtin_amdgcn_s_setprio(0);
  };

  stage(0, 0);
  __syncthreads();
  for (int kt = 0; kt < NTF; kt += 2) {
    stage(kt + 1, 1);
    compute(0);
    __syncthreads();
    if (kt + 2 < NTF) stage(kt + 2, 0);
    compute(1);
    __syncthreads();
  }

  // row-sum over the 4 lg groups (disjoint 8-key partials of q-row lr)
  lsum += __shfl_xor(lsum, 16, 64);
  lsum += __shfl_xor(lsum, 32, 64);
  float inv = 1.0f / lsum;

  // direct output: acc[o][i] = O^T[d = o*16 + lg*4 + i][qrow = lr]
  size_t rowOff = (size_t)(q0 + w * 16 + lr) * 3072 + h * 128;
#pragma unroll
  for (int o = 0; o < 8; o++) {
    f32x4 v = acc[o];
    v[0] *= inv; v[1] *= inv; v[2] *= inv; v[3] *= inv;
    *(f32x4*)&out[rowOff + o * 16 + lg * 4] = v;
  }
}

extern "C" void kernel_launch(void* const* d_in, const int* in_sizes, int n_in,
                              void* d_out, int out_size, void* d_ws, size_t ws_size,
                              hipStream_t stream) {
  const float* hs  = (const float*)d_in[0];
  const float* Wq  = (const float*)d_in[1];
  const float* bq  = (const float*)d_in[2];
  const float* Wk  = (const float*)d_in[3];
  const float* bk  = (const float*)d_in[4];
  const float* Wv  = (const float*)d_in[5];
  const float* bv  = (const float*)d_in[6];
  const float* k_down = (const float*)d_in[9];
  const float* k_up   = (const float*)d_in[10];
  const float* v_down = (const float*)d_in[11];
  const float* v_up   = (const float*)d_in[12];
  const float* nqw = (const float*)d_in[13];
  const float* nkw = (const float*)d_in[14];
  const float* rc  = (const float*)d_in[15];
  const float* rsn = (const float*)d_in[16];
  float* out = (float*)d_out;

  char* ws = (char*)d_ws;
  unsigned short* hsb = (unsigned short*)(ws + 0);          // 13,369,344 B
  unsigned short* wb  = (unsigned short*)(ws + 13369344);   // 56,623,104 B
  float* tkW  = (float*)(ws + 98525184);                    //     65,536 B
  float* tvW  = (float*)(ws + 98590720);                    //     65,536 B
  unsigned short* qh  = (unsigned short*)(ws + 150208512);  //  7,077,888 B
  unsigned short* kh  = (unsigned short*)(ws + 157286400);  // 13,369,344 B
  unsigned short* vtb = (unsigned short*)(ws + 170655744);  // 13,369,344 B

  prep_kernel<<<dim3(NB_CVT + NB_W + NB_LORAT), 256, 0, stream>>>(
      hs, Wq, Wk, Wv, k_down, v_down, hsb, wb, tkW, tvW);

  gemm_kernel<<<dim3(1032), 256, 0, stream>>>(hsb, wb, bq, bk, bv,
                                              tkW, tvW, k_up, v_up,
                                              nqw, nkw, rc, rsn, qh, kh, vtb);
  attn_kernel<<<dim3(18 * NH), 256, 0, stream>>>(qh, kh, vtb, out);
}